// Round 1
// baseline (201.736 us; speedup 1.0000x reference)
//
#include <hip/hip_runtime.h>
#include <hip/hip_bf16.h>

#define K_DIM 4096

// One wave (64 lanes) computes one output row: two dot-products of length 4096.
// Lanes stride over K with float4 loads (16 B/lane -> 1 KiB/instruction, fully
// coalesced). W (4096x2, 32 KB) is staged per-block into LDS, column-split so
// LDS reads are contiguous b128 (conflict-free). Grid-stride over rows.
__global__ __launch_bounds__(256) void moe_rowdot_kernel(
    const float* __restrict__ A,   // [BATCH][K_DIM]
    const float* __restrict__ W,   // [K_DIM][2]
    float* __restrict__ out,       // [BATCH][2]
    int batch) {

    __shared__ float w0[K_DIM];
    __shared__ float w1[K_DIM];

    // Stage W into LDS (column-split). W is row-major [K][2] -> float2 per k.
    for (int i = threadIdx.x; i < K_DIM; i += blockDim.x) {
        float2 wv = reinterpret_cast<const float2*>(W)[i];
        w0[i] = wv.x;
        w1[i] = wv.y;
    }
    __syncthreads();

    const int lane          = threadIdx.x & 63;
    const int waveInBlock   = threadIdx.x >> 6;
    const int wavesPerBlock = blockDim.x >> 6;
    const int globalWave    = blockIdx.x * wavesPerBlock + waveInBlock;
    const int numWaves      = gridDim.x * wavesPerBlock;

    const float4* w0v = reinterpret_cast<const float4*>(w0);
    const float4* w1v = reinterpret_cast<const float4*>(w1);

    for (int row = globalWave; row < batch; row += numWaves) {
        const float4* arow =
            reinterpret_cast<const float4*>(A + (size_t)row * K_DIM);
        float acc0 = 0.f, acc1 = 0.f;
        // K_DIM / (64 lanes * 4 floats) = 16 iterations
        #pragma unroll
        for (int it = 0; it < K_DIM / 256; ++it) {
            const int idx = it * 64 + lane;      // float4 index
            float4 a  = arow[idx];
            float4 b0 = w0v[idx];
            float4 b1 = w1v[idx];
            acc0 += a.x * b0.x + a.y * b0.y + a.z * b0.z + a.w * b0.w;
            acc1 += a.x * b1.x + a.y * b1.y + a.z * b1.z + a.w * b1.w;
        }
        // Wave-wide reduction (64 lanes).
        #pragma unroll
        for (int off = 32; off > 0; off >>= 1) {
            acc0 += __shfl_xor(acc0, off);
            acc1 += __shfl_xor(acc1, off);
        }
        if (lane == 0) {
            reinterpret_cast<float2*>(out)[row] = make_float2(acc0, acc1);
        }
    }
}

extern "C" void kernel_launch(void* const* d_in, const int* in_sizes, int n_in,
                              void* d_out, int out_size, void* d_ws, size_t ws_size,
                              hipStream_t stream) {
    const float* A = (const float*)d_in[0];   // router_weights [65536][4096]
    const float* W = (const float*)d_in[1];   // W_values [4096][2]
    float* out = (float*)d_out;               // [65536][2]

    const int batch = in_sizes[0] / K_DIM;    // 65536

    // 2048 blocks x 256 threads = 8192 waves; 8 rows per wave grid-stride.
    const int blocks = 2048;
    moe_rowdot_kernel<<<blocks, 256, 0, stream>>>(A, W, out, batch);
}